// Round 1
// baseline (286.812 us; speedup 1.0000x reference)
//
#include <hip/hip_runtime.h>
#include <math.h>

constexpr int   B_    = 4;
constexpr int   N_    = 2048;
constexpr int   INF_  = 256;
constexpr int   OUTF_ = 128;
constexpr float ALPHA_       = 0.2f;
constexpr float LAMBDA_INIT_ = 0.35550906759096926f;
constexpr float OUT_SCALE_   = 0.64449093240903074f;   // 1 - LAMBDA_INIT
constexpr float EPS_         = 1e-5f;
constexpr float NEG_         = -9.0e15f;

// ---------------- Kernel A: tiny scalars (rel scores + lambda) ----------------
__global__ void scalars_kernel(const float* __restrict__ rel_emb,
                               const float* __restrict__ a_rel_pos,
                               const float* __restrict__ a_rel_neg,
                               const float* __restrict__ ll1, const float* __restrict__ lr1,
                               const float* __restrict__ ll2, const float* __restrict__ lr2,
                               float* __restrict__ scal) {
  int lane = threadIdx.x;  // 64 threads, 1 wave
  float p1 = ll1[lane] * lr1[lane];
  float p2 = ll2[lane] * lr2[lane];
  #pragma unroll
  for (int off = 32; off; off >>= 1) { p1 += __shfl_xor(p1, off); p2 += __shfl_xor(p2, off); }
  if (lane == 0) scal[12] = expf(p1) - expf(p2) + LAMBDA_INIT_;
  if (lane < 6) {
    float sp = 0.f, sn = 0.f;
    for (int k = 0; k < 10; ++k) {
      float rv = rel_emb[lane * 10 + k];
      sp += rv * a_rel_pos[k];
      sn += rv * a_rel_neg[k];
    }
    scal[lane]     = sp;
    scal[6 + lane] = sn;
  }
}

// ---------------- Kernel B: Wh = h @ W  (fp32) ----------------
// block: 256 threads, 16 rows x 128 cols per block
__global__ __launch_bounds__(256) void wh_kernel(const float* __restrict__ h,
                                                 const float* __restrict__ W,
                                                 float* __restrict__ Wh) {
  __shared__ __align__(16) float hT[INF_][20];  // padded, 16B-aligned float4 at col 0/8
  const int t = threadIdx.x;
  const size_t row0 = (size_t)blockIdx.x * 16;
  #pragma unroll
  for (int i = 0; i < 16; ++i) hT[t][i] = h[(row0 + i) * INF_ + t];
  __syncthreads();
  const int c  = t & 127;
  const int rg = t >> 7;
  float acc[8] = {0.f, 0.f, 0.f, 0.f, 0.f, 0.f, 0.f, 0.f};
  #pragma unroll 4
  for (int k = 0; k < INF_; ++k) {
    float wv = W[k * OUTF_ + c];
    const float4* hp = reinterpret_cast<const float4*>(&hT[k][rg * 8]);
    float4 h0 = hp[0], h1 = hp[1];
    acc[0] += h0.x * wv; acc[1] += h0.y * wv; acc[2] += h0.z * wv; acc[3] += h0.w * wv;
    acc[4] += h1.x * wv; acc[5] += h1.y * wv; acc[6] += h1.z * wv; acc[7] += h1.w * wv;
  }
  #pragma unroll
  for (int r = 0; r < 8; ++r) Wh[(row0 + rg * 8 + r) * OUTF_ + c] = acc[r];
}

// ---------------- Kernel C: per-node dot scores ----------------
// block: 256 threads = 4 waves, one node per wave
__global__ __launch_bounds__(256) void dots_kernel(const float* __restrict__ Wh,
                                                   const float* __restrict__ alp, const float* __restrict__ arp,
                                                   const float* __restrict__ aln, const float* __restrict__ arn,
                                                   float* __restrict__ lposv, float* __restrict__ rposv,
                                                   float* __restrict__ lnegv, float* __restrict__ rnegv) {
  const int t = threadIdx.x;
  const int wid = t >> 6, lane = t & 63;
  const int node = blockIdx.x * 4 + wid;
  float wp = Wh[(size_t)node * OUTF_ + lane];
  float wn = Wh[(size_t)node * OUTF_ + 64 + lane];
  float s0 = wp * alp[lane], s1 = wp * arp[lane];
  float s2 = wn * aln[lane], s3 = wn * arn[lane];
  #pragma unroll
  for (int off = 32; off; off >>= 1) {
    s0 += __shfl_xor(s0, off); s1 += __shfl_xor(s1, off);
    s2 += __shfl_xor(s2, off); s3 += __shfl_xor(s3, off);
  }
  if (lane == 0) { lposv[node] = s0; rposv[node] = s1; lnegv[node] = s2; rnegv[node] = s3; }
}

// ---------------- Kernel D: fused attention + PV + LN + GELU ----------------
// block: 256 threads, 8 rows per block. LDS = exactly 64KB (attn tile, scratch folded in).
__global__ __launch_bounds__(256) void attn_kernel(
    const int* __restrict__ adj, const float* __restrict__ Wh,
    const float* __restrict__ lposv, const float* __restrict__ rposv,
    const float* __restrict__ lnegv, const float* __restrict__ rnegv,
    const float* __restrict__ scal, const float* __restrict__ gamma,
    const float* __restrict__ beta, float* __restrict__ out0, float* __restrict__ out1) {
  __shared__ __align__(16) float attnL[N_ * 8];  // [j][r] packed, 64KB
  const int t = threadIdx.x;
  const int lane = t & 63;
  const int wid = t >> 6;
  const int bi = blockIdx.x;
  const int b = bi >> 8;
  const int i0 = (bi & 255) * 8;

  const float relP1 = scal[1], relP2 = scal[2], relP3 = scal[3], relP4 = scal[4], relP5 = scal[5];
  const float relN1 = scal[7], relN2 = scal[8], relN3 = scal[9], relN4 = scal[10], relN5 = scal[11];
  const float lam = scal[12];

  // hoist right scores for this thread's 8 columns (shared across the 8 rows)
  float rpv[8], rnv[8];
  #pragma unroll
  for (int s = 0; s < 8; ++s) {
    int j = t + s * 256;
    rpv[s] = rposv[b * N_ + j];
    rnv[s] = rnegv[b * N_ + j];
  }

  for (int r = 0; r < 8; ++r) {
    const int i = i0 + r;
    const float lP = lposv[b * N_ + i];
    const float lN = lnegv[b * N_ + i];
    const int* adjRow = adj + (size_t)(b * N_ + i) * N_;
    float eP[8], eN[8];
    float mP = -3.4e38f, mN = -3.4e38f;
    #pragma unroll
    for (int s = 0; s < 8; ++s) {
      int j = t + s * 256;
      int av = adjRow[j];
      float rsp = (av == 1) ? relP1 : (av == 2) ? relP2 : (av == 3) ? relP3 : (av == 4) ? relP4 : relP5;
      float rsn = (av == 1) ? relN1 : (av == 2) ? relN2 : (av == 3) ? relN3 : (av == 4) ? relN4 : relN5;
      float ep = lP + rpv[s] + rsp;
      ep = (ep >= 0.f) ? ep : ALPHA_ * ep;
      float en = lN + rnv[s] + rsn;
      en = (en >= 0.f) ? en : ALPHA_ * en;
      if (av == 0) { ep = NEG_; en = NEG_; }
      eP[s] = ep; eN[s] = en;
      mP = fmaxf(mP, ep); mN = fmaxf(mN, en);
    }
    #pragma unroll
    for (int off = 32; off; off >>= 1) { mP = fmaxf(mP, __shfl_xor(mP, off)); mN = fmaxf(mN, __shfl_xor(mN, off)); }
    if (lane == 0) { attnL[wid * 8 + r] = mP; attnL[(4 + wid) * 8 + r] = mN; }
    __syncthreads();
    if (t == 0) {
      float MPc = attnL[r], MNc = attnL[32 + r];
      for (int w = 1; w < 4; ++w) { MPc = fmaxf(MPc, attnL[w * 8 + r]); MNc = fmaxf(MNc, attnL[(4 + w) * 8 + r]); }
      attnL[r] = MPc; attnL[8 + r] = MNc;
    }
    __syncthreads();
    const float MP = attnL[r], MN = attnL[8 + r];
    float sP = 0.f, sN = 0.f;
    #pragma unroll
    for (int s = 0; s < 8; ++s) { sP += __expf(eP[s] - MP); sN += __expf(eN[s] - MN); }
    #pragma unroll
    for (int off = 32; off; off >>= 1) { sP += __shfl_xor(sP, off); sN += __shfl_xor(sN, off); }
    __syncthreads();  // all broadcast-max reads done before scratch reuse
    if (lane == 0) { attnL[wid * 8 + r] = sP; attnL[(4 + wid) * 8 + r] = sN; }
    __syncthreads();
    if (t == 0) {
      float SP = 0.f, SN = 0.f;
      for (int w = 0; w < 4; ++w) { SP += attnL[w * 8 + r]; SN += attnL[(4 + w) * 8 + r]; }
      attnL[r] = SP; attnL[8 + r] = SN;
    }
    __syncthreads();
    const float invSP = 1.f / attnL[r];
    const float invSN = 1.f / attnL[8 + r];
    __syncthreads();  // broadcast-sum reads done before attn overwrites slots
    float* outRow = out1 + (size_t)(b * N_ + i) * N_;
    #pragma unroll
    for (int s = 0; s < 8; ++s) {
      int j = t + s * 256;
      float a = __expf(eP[s] - MP) * invSP - lam * (__expf(eN[s] - MN) * invSN);
      attnL[j * 8 + r] = a;
      outRow[j] = a;
    }
  }
  __syncthreads();

  // ---- phase 2: h_prime = attention @ Wh_v ----
  const int ch = t & 127;
  const int half = t >> 7;
  const float* WhB = Wh + (size_t)b * N_ * OUTF_;
  float acc[8] = {0.f, 0.f, 0.f, 0.f, 0.f, 0.f, 0.f, 0.f};
  #pragma unroll 4
  for (int jj = 0; jj < N_ / 2; ++jj) {
    int j = (half << 10) + jj;
    float wv = WhB[(size_t)j * OUTF_ + ch];
    const float4* ap = reinterpret_cast<const float4*>(&attnL[j * 8]);
    float4 a0 = ap[0], a1 = ap[1];
    acc[0] += a0.x * wv; acc[1] += a0.y * wv; acc[2] += a0.z * wv; acc[3] += a0.w * wv;
    acc[4] += a1.x * wv; acc[5] += a1.y * wv; acc[6] += a1.z * wv; acc[7] += a1.w * wv;
  }
  __syncthreads();  // attnL reads done; reuse as scratch
  if (half == 1) {
    #pragma unroll
    for (int r = 0; r < 8; ++r) attnL[ch * 8 + r] = acc[r];
  }
  __syncthreads();
  float tot[8];
  if (half == 0) {
    #pragma unroll
    for (int r = 0; r < 8; ++r) tot[r] = acc[r] + attnL[ch * 8 + r];
  }
  const float gm = gamma[ch], bt = beta[ch];
  for (int r = 0; r < 8; ++r) {
    float x = (half == 0) ? tot[r] : 0.f;
    float s = x, q = x * x;
    #pragma unroll
    for (int off = 32; off; off >>= 1) { s += __shfl_xor(s, off); q += __shfl_xor(q, off); }
    if (lane == 0) { attnL[4096 + wid * 2] = s; attnL[4096 + wid * 2 + 1] = q; }
    __syncthreads();
    if (t == 0) {
      float S = 0.f, Q = 0.f;
      for (int w = 0; w < 4; ++w) { S += attnL[4096 + w * 2]; Q += attnL[4096 + w * 2 + 1]; }
      attnL[4104] = S; attnL[4105] = Q;
    }
    __syncthreads();
    const float mu  = attnL[4104] * (1.f / 128.f);
    const float var = attnL[4105] * (1.f / 128.f) - mu * mu;
    const float inv = rsqrtf(var + EPS_);
    if (half == 0) {
      float y = (tot[r] - mu) * inv * gm + bt;
      y *= OUT_SCALE_;
      float g = 0.5f * y * (1.f + erff(y * 0.70710678118654752f));
      out0[(size_t)(b * N_ + i0 + r) * OUTF_ + ch] = g;
    }
    __syncthreads();
  }
}

extern "C" void kernel_launch(void* const* d_in, const int* in_sizes, int n_in,
                              void* d_out, int out_size, void* d_ws, size_t ws_size,
                              hipStream_t stream) {
  (void)in_sizes; (void)n_in; (void)out_size; (void)ws_size;
  const float* h        = (const float*)d_in[0];
  const int*   adj      = (const int*)d_in[1];
  const float* W        = (const float*)d_in[2];
  const float* alp      = (const float*)d_in[3];
  const float* arp      = (const float*)d_in[4];
  const float* aln      = (const float*)d_in[5];
  const float* arn      = (const float*)d_in[6];
  const float* rel_emb  = (const float*)d_in[7];
  const float* a_rel_p  = (const float*)d_in[8];
  const float* a_rel_n  = (const float*)d_in[9];
  const float* ll1      = (const float*)d_in[10];
  const float* lr1      = (const float*)d_in[11];
  const float* ll2      = (const float*)d_in[12];
  const float* lr2      = (const float*)d_in[13];
  const float* gamma    = (const float*)d_in[14];
  const float* beta     = (const float*)d_in[15];

  float* out0 = (float*)d_out;                          // gelu(h'): B*N*OUTF
  float* out1 = out0 + (size_t)B_ * N_ * OUTF_;         // attention: B*N*N

  float* ws    = (float*)d_ws;
  float* scal  = ws;                    // 16 floats
  float* lposv = ws + 16;               // B*N
  float* rposv = lposv + B_ * N_;
  float* lnegv = rposv + B_ * N_;
  float* rnegv = lnegv + B_ * N_;
  float* Wh    = rnegv + B_ * N_;       // B*N*OUTF

  scalars_kernel<<<1, 64, 0, stream>>>(rel_emb, a_rel_p, a_rel_n, ll1, lr1, ll2, lr2, scal);
  wh_kernel<<<(B_ * N_) / 16, 256, 0, stream>>>(h, W, Wh);
  dots_kernel<<<(B_ * N_) / 4, 256, 0, stream>>>(Wh, alp, arp, aln, arn, lposv, rposv, lnegv, rnegv);
  attn_kernel<<<B_ * (N_ / 8), 256, 0, stream>>>(adj, Wh, lposv, rposv, lnegv, rnegv,
                                                 scal, gamma, beta, out0, out1);
}

// Round 2
// 188.671 us; speedup vs baseline: 1.5202x; 1.5202x over previous
//
#include <hip/hip_runtime.h>
#include <math.h>

constexpr int   B_    = 4;
constexpr int   N_    = 2048;
constexpr int   INF_  = 256;
constexpr int   OUTF_ = 128;
constexpr float ALPHA_       = 0.2f;
constexpr float LAMBDA_INIT_ = 0.35550906759096926f;
constexpr float OUT_SCALE_   = 0.64449093240903074f;   // 1 - LAMBDA_INIT
constexpr float EPS_         = 1e-5f;
constexpr float NEG_         = -9.0e15f;

// ---------------- Kernel A: tiny scalars (rel scores + lambda) ----------------
__global__ void scalars_kernel(const float* __restrict__ rel_emb,
                               const float* __restrict__ a_rel_pos,
                               const float* __restrict__ a_rel_neg,
                               const float* __restrict__ ll1, const float* __restrict__ lr1,
                               const float* __restrict__ ll2, const float* __restrict__ lr2,
                               float* __restrict__ scal) {
  int lane = threadIdx.x;  // 64 threads, 1 wave
  float p1 = ll1[lane] * lr1[lane];
  float p2 = ll2[lane] * lr2[lane];
  #pragma unroll
  for (int off = 32; off; off >>= 1) { p1 += __shfl_xor(p1, off); p2 += __shfl_xor(p2, off); }
  if (lane == 0) scal[12] = expf(p1) - expf(p2) + LAMBDA_INIT_;
  if (lane < 6) {
    float sp = 0.f, sn = 0.f;
    for (int k = 0; k < 10; ++k) {
      float rv = rel_emb[lane * 10 + k];
      sp += rv * a_rel_pos[k];
      sn += rv * a_rel_neg[k];
    }
    scal[lane]     = sp;
    scal[6 + lane] = sn;
  }
}

// ---------------- Kernel B: Wh = h @ W  (fp32) ----------------
__global__ __launch_bounds__(256) void wh_kernel(const float* __restrict__ h,
                                                 const float* __restrict__ W,
                                                 float* __restrict__ Wh) {
  __shared__ __align__(16) float hT[INF_][20];
  const int t = threadIdx.x;
  const size_t row0 = (size_t)blockIdx.x * 16;
  #pragma unroll
  for (int i = 0; i < 16; ++i) hT[t][i] = h[(row0 + i) * INF_ + t];
  __syncthreads();
  const int c  = t & 127;
  const int rg = t >> 7;
  float acc[8] = {0.f, 0.f, 0.f, 0.f, 0.f, 0.f, 0.f, 0.f};
  #pragma unroll 4
  for (int k = 0; k < INF_; ++k) {
    float wv = W[k * OUTF_ + c];
    const float4* hp = reinterpret_cast<const float4*>(&hT[k][rg * 8]);
    float4 h0 = hp[0], h1 = hp[1];
    acc[0] += h0.x * wv; acc[1] += h0.y * wv; acc[2] += h0.z * wv; acc[3] += h0.w * wv;
    acc[4] += h1.x * wv; acc[5] += h1.y * wv; acc[6] += h1.z * wv; acc[7] += h1.w * wv;
  }
  #pragma unroll
  for (int r = 0; r < 8; ++r) Wh[(row0 + rg * 8 + r) * OUTF_ + c] = acc[r];
}

// ---------------- Kernel C: per-node dot scores ----------------
__global__ __launch_bounds__(256) void dots_kernel(const float* __restrict__ Wh,
                                                   const float* __restrict__ alp, const float* __restrict__ arp,
                                                   const float* __restrict__ aln, const float* __restrict__ arn,
                                                   float* __restrict__ lposv, float* __restrict__ rposv,
                                                   float* __restrict__ lnegv, float* __restrict__ rnegv) {
  const int t = threadIdx.x;
  const int wid = t >> 6, lane = t & 63;
  const int node = blockIdx.x * 4 + wid;
  float wp = Wh[(size_t)node * OUTF_ + lane];
  float wn = Wh[(size_t)node * OUTF_ + 64 + lane];
  float s0 = wp * alp[lane], s1 = wp * arp[lane];
  float s2 = wn * aln[lane], s3 = wn * arn[lane];
  #pragma unroll
  for (int off = 32; off; off >>= 1) {
    s0 += __shfl_xor(s0, off); s1 += __shfl_xor(s1, off);
    s2 += __shfl_xor(s2, off); s3 += __shfl_xor(s3, off);
  }
  if (lane == 0) { lposv[node] = s0; rposv[node] = s1; lnegv[node] = s2; rnegv[node] = s3; }
}

// ---------------- Kernel D1: attention rows (one wave per row, no LDS) ----------------
// block: 256 threads = 4 waves, one row per wave; 32 columns per lane.
__global__ __launch_bounds__(256) void attn_rows_kernel(
    const int* __restrict__ adj,
    const float* __restrict__ lposv, const float* __restrict__ rposv,
    const float* __restrict__ lnegv, const float* __restrict__ rnegv,
    const float* __restrict__ scal, float* __restrict__ out1) {
  const int t = threadIdx.x;
  const int lane = t & 63;
  const int wid = t >> 6;
  const int flat = blockIdx.x * 4 + wid;   // b*N + i
  const int b = flat >> 11;

  const float relP1 = scal[1], relP2 = scal[2], relP3 = scal[3], relP4 = scal[4], relP5 = scal[5];
  const float relN1 = scal[7], relN2 = scal[8], relN3 = scal[9], relN4 = scal[10], relN5 = scal[11];
  const float lam = scal[12];

  const float lP = lposv[flat];
  const float lN = lnegv[flat];
  const int4*   adj4 = reinterpret_cast<const int4*>(adj + (size_t)flat * N_);
  const float4* rp4  = reinterpret_cast<const float4*>(rposv + b * N_);
  const float4* rn4  = reinterpret_cast<const float4*>(rnegv + b * N_);

  float eP[32], eN[32];
  float mP = -3.4e38f, mN = -3.4e38f;
  #pragma unroll
  for (int k = 0; k < 8; ++k) {
    const int idx = lane + k * 64;
    int4   av = adj4[idx];
    float4 rp = rp4[idx];
    float4 rn = rn4[idx];
    int   avi[4] = {av.x, av.y, av.z, av.w};
    float rpi[4] = {rp.x, rp.y, rp.z, rp.w};
    float rni[4] = {rn.x, rn.y, rn.z, rn.w};
    #pragma unroll
    for (int c = 0; c < 4; ++c) {
      int a = avi[c];
      float rsp = (a == 1) ? relP1 : (a == 2) ? relP2 : (a == 3) ? relP3 : (a == 4) ? relP4 : relP5;
      float rsn = (a == 1) ? relN1 : (a == 2) ? relN2 : (a == 3) ? relN3 : (a == 4) ? relN4 : relN5;
      float ep = lP + rpi[c] + rsp;
      ep = (ep >= 0.f) ? ep : ALPHA_ * ep;
      float en = lN + rni[c] + rsn;
      en = (en >= 0.f) ? en : ALPHA_ * en;
      if (a == 0) { ep = NEG_; en = NEG_; }
      eP[k * 4 + c] = ep; eN[k * 4 + c] = en;
      mP = fmaxf(mP, ep); mN = fmaxf(mN, en);
    }
  }
  #pragma unroll
  for (int off = 32; off; off >>= 1) {
    mP = fmaxf(mP, __shfl_xor(mP, off));
    mN = fmaxf(mN, __shfl_xor(mN, off));
  }
  float sP = 0.f, sN = 0.f;
  #pragma unroll
  for (int q = 0; q < 32; ++q) {
    float p = __expf(eP[q] - mP); eP[q] = p; sP += p;
    float n = __expf(eN[q] - mN); eN[q] = n; sN += n;
  }
  #pragma unroll
  for (int off = 32; off; off >>= 1) {
    sP += __shfl_xor(sP, off);
    sN += __shfl_xor(sN, off);
  }
  const float invSP = 1.f / sP;
  const float nlamSN = -lam / sN;
  float4* out4 = reinterpret_cast<float4*>(out1 + (size_t)flat * N_);
  #pragma unroll
  for (int k = 0; k < 8; ++k) {
    float4 a;
    a.x = eP[k * 4 + 0] * invSP + eN[k * 4 + 0] * nlamSN;
    a.y = eP[k * 4 + 1] * invSP + eN[k * 4 + 1] * nlamSN;
    a.z = eP[k * 4 + 2] * invSP + eN[k * 4 + 2] * nlamSN;
    a.w = eP[k * 4 + 3] * invSP + eN[k * 4 + 3] * nlamSN;
    out4[lane + k * 64] = a;
  }
}

// ---------------- Kernel D2: h_prime = attention @ Wh_v, then LN + GELU ----------------
// block: 256 threads = (ch 0..127) x (jhalf 0..1); 8 rows per block.
// attention chunks streamed through an 8KB LDS tile aT[jj][8].
__global__ __launch_bounds__(256) void pv_kernel(
    const float* __restrict__ attn, const float* __restrict__ Wh,
    const float* __restrict__ gamma, const float* __restrict__ beta,
    float* __restrict__ out0) {
  __shared__ __align__(16) float aT[256][8];   // [jj within chunk][row]
  __shared__ float lnS[18];
  const int t = threadIdx.x;
  const int lane = t & 63;
  const int wid = t >> 6;
  const int bi = blockIdx.x;
  const int b = bi >> 8;
  const int i0 = (bi & 255) * 8;

  const int ch = t & 127;
  const int hf = t >> 7;
  const float* WhB = Wh + (size_t)b * N_ * OUTF_;
  const float* attnBase = attn + ((size_t)(b * N_ + i0)) * N_;

  float acc[8] = {0.f, 0.f, 0.f, 0.f, 0.f, 0.f, 0.f, 0.f};

  for (int c = 0; c < 8; ++c) {
    const int j0 = c * 256;
    // cooperative load: thread t fetches column j0+t of 8 attention rows
    float4 v0, v1;
    {
      float vr[8];
      #pragma unroll
      for (int r = 0; r < 8; ++r) vr[r] = attnBase[(size_t)r * N_ + j0 + t];
      v0 = make_float4(vr[0], vr[1], vr[2], vr[3]);
      v1 = make_float4(vr[4], vr[5], vr[6], vr[7]);
    }
    __syncthreads();   // previous chunk fully consumed
    float4* dst = reinterpret_cast<float4*>(&aT[t][0]);
    dst[0] = v0; dst[1] = v1;
    __syncthreads();   // tile ready
    // compute: each thread covers 128 j's of this chunk
    #pragma unroll 4
    for (int jj = 0; jj < 128; ++jj) {
      const int jLoc = hf * 128 + jj;
      const int j = j0 + jLoc;
      float wv = WhB[(size_t)j * OUTF_ + ch];
      const float4* ap = reinterpret_cast<const float4*>(&aT[jLoc][0]);
      float4 a0 = ap[0], a1 = ap[1];
      acc[0] += a0.x * wv; acc[1] += a0.y * wv; acc[2] += a0.z * wv; acc[3] += a0.w * wv;
      acc[4] += a1.x * wv; acc[5] += a1.y * wv; acc[6] += a1.z * wv; acc[7] += a1.w * wv;
    }
  }
  __syncthreads();  // all aT reads done; reuse as scratch

  // combine halves: half 1 deposits, half 0 adds
  if (hf == 1) {
    #pragma unroll
    for (int r = 0; r < 8; ++r) aT[ch][r] = acc[r];
  }
  __syncthreads();
  float tot[8];
  if (hf == 0) {
    #pragma unroll
    for (int r = 0; r < 8; ++r) tot[r] = acc[r] + aT[ch][r];
  }

  const float gm = gamma[ch], bt = beta[ch];
  for (int r = 0; r < 8; ++r) {
    float x = (hf == 0) ? tot[r] : 0.f;
    float s = x, q = x * x;
    #pragma unroll
    for (int off = 32; off; off >>= 1) { s += __shfl_xor(s, off); q += __shfl_xor(q, off); }
    if (lane == 0) { lnS[wid * 2] = s; lnS[wid * 2 + 1] = q; }
    __syncthreads();
    if (t == 0) {
      float S = 0.f, Q = 0.f;
      for (int w = 0; w < 4; ++w) { S += lnS[w * 2]; Q += lnS[w * 2 + 1]; }
      lnS[16] = S; lnS[17] = Q;
    }
    __syncthreads();
    const float mu  = lnS[16] * (1.f / 128.f);
    const float var = lnS[17] * (1.f / 128.f) - mu * mu;
    const float inv = rsqrtf(var + EPS_);
    if (hf == 0) {
      float y = (tot[r] - mu) * inv * gm + bt;
      y *= OUT_SCALE_;
      float g = 0.5f * y * (1.f + erff(y * 0.70710678118654752f));
      out0[(size_t)(b * N_ + i0 + r) * OUTF_ + ch] = g;
    }
    __syncthreads();
  }
}

extern "C" void kernel_launch(void* const* d_in, const int* in_sizes, int n_in,
                              void* d_out, int out_size, void* d_ws, size_t ws_size,
                              hipStream_t stream) {
  (void)in_sizes; (void)n_in; (void)out_size; (void)ws_size;
  const float* h        = (const float*)d_in[0];
  const int*   adj      = (const int*)d_in[1];
  const float* W        = (const float*)d_in[2];
  const float* alp      = (const float*)d_in[3];
  const float* arp      = (const float*)d_in[4];
  const float* aln      = (const float*)d_in[5];
  const float* arn      = (const float*)d_in[6];
  const float* rel_emb  = (const float*)d_in[7];
  const float* a_rel_p  = (const float*)d_in[8];
  const float* a_rel_n  = (const float*)d_in[9];
  const float* ll1      = (const float*)d_in[10];
  const float* lr1      = (const float*)d_in[11];
  const float* ll2      = (const float*)d_in[12];
  const float* lr2      = (const float*)d_in[13];
  const float* gamma    = (const float*)d_in[14];
  const float* beta     = (const float*)d_in[15];

  float* out0 = (float*)d_out;                          // gelu(h'): B*N*OUTF
  float* out1 = out0 + (size_t)B_ * N_ * OUTF_;         // attention: B*N*N

  float* ws    = (float*)d_ws;
  float* scal  = ws;                    // 16 floats
  float* lposv = ws + 16;               // B*N
  float* rposv = lposv + B_ * N_;
  float* lnegv = rposv + B_ * N_;
  float* rnegv = lnegv + B_ * N_;
  float* Wh    = rnegv + B_ * N_;       // B*N*OUTF

  scalars_kernel<<<1, 64, 0, stream>>>(rel_emb, a_rel_p, a_rel_n, ll1, lr1, ll2, lr2, scal);
  wh_kernel<<<(B_ * N_) / 16, 256, 0, stream>>>(h, W, Wh);
  dots_kernel<<<(B_ * N_) / 4, 256, 0, stream>>>(Wh, alp, arp, aln, arn, lposv, rposv, lnegv, rnegv);
  attn_rows_kernel<<<(B_ * N_) / 4, 256, 0, stream>>>(adj, lposv, rposv, lnegv, rnegv, scal, out1);
  pv_kernel<<<B_ * (N_ / 8), 256, 0, stream>>>(out1, Wh, gamma, beta, out0);
}

// Round 3
// 128.503 us; speedup vs baseline: 2.2320x; 1.4682x over previous
//
#include <hip/hip_runtime.h>
#include <math.h>

typedef short bf16x8 __attribute__((ext_vector_type(8)));
typedef float f32x4  __attribute__((ext_vector_type(4)));

constexpr int   B_    = 4;
constexpr int   N_    = 2048;
constexpr int   INF_  = 256;
constexpr int   OUTF_ = 128;
constexpr float ALPHA_       = 0.2f;
constexpr float LAMBDA_INIT_ = 0.35550906759096926f;
constexpr float OUT_SCALE_   = 0.64449093240903074f;   // 1 - LAMBDA_INIT
constexpr float EPS_         = 1e-5f;
constexpr float NEG_         = -9.0e15f;

__device__ inline unsigned short f2bf(float x) {
  unsigned u = __float_as_uint(x);
  u += 0x7fffu + ((u >> 16) & 1u);          // round-to-nearest-even
  return (unsigned short)(u >> 16);
}
__device__ inline unsigned pack2(float a, float b) {
  return (unsigned)f2bf(a) | ((unsigned)f2bf(b) << 16);
}

// ---------------- Kernel A: tiny scalars (rel scores + lambda) ----------------
__global__ void scalars_kernel(const float* __restrict__ rel_emb,
                               const float* __restrict__ a_rel_pos,
                               const float* __restrict__ a_rel_neg,
                               const float* __restrict__ ll1, const float* __restrict__ lr1,
                               const float* __restrict__ ll2, const float* __restrict__ lr2,
                               float* __restrict__ scal) {
  int lane = threadIdx.x;  // 64 threads, 1 wave
  float p1 = ll1[lane] * lr1[lane];
  float p2 = ll2[lane] * lr2[lane];
  #pragma unroll
  for (int off = 32; off; off >>= 1) { p1 += __shfl_xor(p1, off); p2 += __shfl_xor(p2, off); }
  if (lane == 0) scal[12] = expf(p1) - expf(p2) + LAMBDA_INIT_;
  if (lane < 6) {
    float sp = 0.f, sn = 0.f;
    for (int k = 0; k < 10; ++k) {
      float rv = rel_emb[lane * 10 + k];
      sp += rv * a_rel_pos[k];
      sn += rv * a_rel_neg[k];
    }
    scal[lane]     = sp;
    scal[6 + lane] = sn;
  }
}

// ---------------- Kernel B: Wh = h @ W (fp32) + transposed bf16 copy ----------------
__global__ __launch_bounds__(256) void wh_kernel(const float* __restrict__ h,
                                                 const float* __restrict__ W,
                                                 float* __restrict__ Wh,
                                                 unsigned short* __restrict__ WhvT) {
  __shared__ __align__(16) float hT[INF_][20];
  const int t = threadIdx.x;
  const size_t row0 = (size_t)blockIdx.x * 16;
  #pragma unroll
  for (int i = 0; i < 16; ++i) hT[t][i] = h[(row0 + i) * INF_ + t];
  __syncthreads();
  const int c  = t & 127;
  const int rg = t >> 7;
  float acc[8] = {0.f, 0.f, 0.f, 0.f, 0.f, 0.f, 0.f, 0.f};
  #pragma unroll 4
  for (int k = 0; k < INF_; ++k) {
    float wv = W[k * OUTF_ + c];
    const float4* hp = reinterpret_cast<const float4*>(&hT[k][rg * 8]);
    float4 h0 = hp[0], h1 = hp[1];
    acc[0] += h0.x * wv; acc[1] += h0.y * wv; acc[2] += h0.z * wv; acc[3] += h0.w * wv;
    acc[4] += h1.x * wv; acc[5] += h1.y * wv; acc[6] += h1.z * wv; acc[7] += h1.w * wv;
  }
  #pragma unroll
  for (int r = 0; r < 8; ++r) Wh[(row0 + rg * 8 + r) * OUTF_ + c] = acc[r];
  // bf16 transposed copy: WhvT[b][c][n], 8 consecutive n per thread = one 16B store
  uint4 pk;
  pk.x = pack2(acc[0], acc[1]); pk.y = pack2(acc[2], acc[3]);
  pk.z = pack2(acc[4], acc[5]); pk.w = pack2(acc[6], acc[7]);
  const int b  = (int)(row0 >> 11);
  const int n0 = (int)(row0 & 2047) + rg * 8;
  *reinterpret_cast<uint4*>(WhvT + ((size_t)b * OUTF_ + c) * N_ + n0) = pk;
}

// ---------------- Kernel C: per-node dot scores ----------------
__global__ __launch_bounds__(256) void dots_kernel(const float* __restrict__ Wh,
                                                   const float* __restrict__ alp, const float* __restrict__ arp,
                                                   const float* __restrict__ aln, const float* __restrict__ arn,
                                                   float* __restrict__ lposv, float* __restrict__ rposv,
                                                   float* __restrict__ lnegv, float* __restrict__ rnegv) {
  const int t = threadIdx.x;
  const int wid = t >> 6, lane = t & 63;
  const int node = blockIdx.x * 4 + wid;
  float wp = Wh[(size_t)node * OUTF_ + lane];
  float wn = Wh[(size_t)node * OUTF_ + 64 + lane];
  float s0 = wp * alp[lane], s1 = wp * arp[lane];
  float s2 = wn * aln[lane], s3 = wn * arn[lane];
  #pragma unroll
  for (int off = 32; off; off >>= 1) {
    s0 += __shfl_xor(s0, off); s1 += __shfl_xor(s1, off);
    s2 += __shfl_xor(s2, off); s3 += __shfl_xor(s3, off);
  }
  if (lane == 0) { lposv[node] = s0; rposv[node] = s1; lnegv[node] = s2; rnegv[node] = s3; }
}

// ---------------- Kernel D1: attention rows (one wave per row, no LDS) ----------------
__global__ __launch_bounds__(256) void attn_rows_kernel(
    const int* __restrict__ adj,
    const float* __restrict__ lposv, const float* __restrict__ rposv,
    const float* __restrict__ lnegv, const float* __restrict__ rnegv,
    const float* __restrict__ scal, float* __restrict__ out1) {
  const int t = threadIdx.x;
  const int lane = t & 63;
  const int wid = t >> 6;
  const int flat = blockIdx.x * 4 + wid;   // b*N + i
  const int b = flat >> 11;

  const float relP1 = scal[1], relP2 = scal[2], relP3 = scal[3], relP4 = scal[4], relP5 = scal[5];
  const float relN1 = scal[7], relN2 = scal[8], relN3 = scal[9], relN4 = scal[10], relN5 = scal[11];
  const float lam = scal[12];

  const float lP = lposv[flat];
  const float lN = lnegv[flat];
  const int4*   adj4 = reinterpret_cast<const int4*>(adj + (size_t)flat * N_);
  const float4* rp4  = reinterpret_cast<const float4*>(rposv + b * N_);
  const float4* rn4  = reinterpret_cast<const float4*>(rnegv + b * N_);

  float eP[32], eN[32];
  float mP = -3.4e38f, mN = -3.4e38f;
  #pragma unroll
  for (int k = 0; k < 8; ++k) {
    const int idx = lane + k * 64;
    int4   av = adj4[idx];
    float4 rp = rp4[idx];
    float4 rn = rn4[idx];
    int   avi[4] = {av.x, av.y, av.z, av.w};
    float rpi[4] = {rp.x, rp.y, rp.z, rp.w};
    float rni[4] = {rn.x, rn.y, rn.z, rn.w};
    #pragma unroll
    for (int c = 0; c < 4; ++c) {
      int a = avi[c];
      float rsp = (a == 1) ? relP1 : (a == 2) ? relP2 : (a == 3) ? relP3 : (a == 4) ? relP4 : relP5;
      float rsn = (a == 1) ? relN1 : (a == 2) ? relN2 : (a == 3) ? relN3 : (a == 4) ? relN4 : relN5;
      float ep = lP + rpi[c] + rsp;
      ep = (ep >= 0.f) ? ep : ALPHA_ * ep;
      float en = lN + rni[c] + rsn;
      en = (en >= 0.f) ? en : ALPHA_ * en;
      if (a == 0) { ep = NEG_; en = NEG_; }
      eP[k * 4 + c] = ep; eN[k * 4 + c] = en;
      mP = fmaxf(mP, ep); mN = fmaxf(mN, en);
    }
  }
  #pragma unroll
  for (int off = 32; off; off >>= 1) {
    mP = fmaxf(mP, __shfl_xor(mP, off));
    mN = fmaxf(mN, __shfl_xor(mN, off));
  }
  float sP = 0.f, sN = 0.f;
  #pragma unroll
  for (int q = 0; q < 32; ++q) {
    float p = __expf(eP[q] - mP); eP[q] = p; sP += p;
    float n = __expf(eN[q] - mN); eN[q] = n; sN += n;
  }
  #pragma unroll
  for (int off = 32; off; off >>= 1) {
    sP += __shfl_xor(sP, off);
    sN += __shfl_xor(sN, off);
  }
  const float invSP = 1.f / sP;
  const float nlamSN = -lam / sN;
  float4* out4 = reinterpret_cast<float4*>(out1 + (size_t)flat * N_);
  #pragma unroll
  for (int k = 0; k < 8; ++k) {
    float4 a;
    a.x = eP[k * 4 + 0] * invSP + eN[k * 4 + 0] * nlamSN;
    a.y = eP[k * 4 + 1] * invSP + eN[k * 4 + 1] * nlamSN;
    a.z = eP[k * 4 + 2] * invSP + eN[k * 4 + 2] * nlamSN;
    a.w = eP[k * 4 + 3] * invSP + eN[k * 4 + 3] * nlamSN;
    out4[lane + k * 64] = a;
  }
}

// ---------------- Kernel D2: PV via MFMA + LN + GELU ----------------
// 512 blocks, 256 threads = 4 waves. Block: 16 rows x 128 ch, K = 2048 in 8 chunks of 256.
// A (attention) staged fp32->bf16 into XOR-swizzled LDS; B (WhvT bf16) loaded direct 16B/lane.
__global__ __launch_bounds__(256) void pv_mfma_kernel(
    const float* __restrict__ attn, const unsigned short* __restrict__ WhvT,
    const float* __restrict__ gamma, const float* __restrict__ beta,
    float* __restrict__ out0) {
  __shared__ __align__(16) uint4 A4[2][16 * 32];   // [buf][row*32 + unit(16B)], 16KB
  __shared__ __align__(16) float hp[16][132];
  const int t = threadIdx.x;
  const int lane = t & 63;
  const int w = t >> 6;
  const int bi = blockIdx.x;
  const int b  = bi >> 7;
  const int i0 = (bi & 127) * 16;

  // ---- staging coords: thread covers row sr, 16 floats starting at col sj*16
  const int sr = t >> 4;
  const int sj = t & 15;
  const float4* src4 = reinterpret_cast<const float4*>(
      attn + ((size_t)(b * N_ + i0 + sr)) * N_ + sj * 16);
  const int swz = sr & 7;
  const int u0i = sr * 32 + ((sj * 2)     ^ swz);
  const int u1i = sr * 32 + ((sj * 2 + 1) ^ swz);

  // ---- compute coords
  const int ch0 = w * 32;
  const int bl  = lane & 15;   // A row / B ch within tile
  const int kg  = lane >> 4;   // k-group
  const unsigned short* Bp0 = WhvT + ((size_t)b * OUTF_ + ch0 + bl) * N_ + kg * 8;
  const unsigned short* Bp1 = Bp0 + (size_t)16 * N_;
  f32x4 acc0 = {0.f, 0.f, 0.f, 0.f};
  f32x4 acc1 = {0.f, 0.f, 0.f, 0.f};
  const int arow = bl * 32;
  const int aswz = bl & 7;

  // stage chunk 0
  {
    float4 s0 = src4[0], s1 = src4[1], s2 = src4[2], s3 = src4[3];
    uint4 u0, u1;
    u0.x = pack2(s0.x, s0.y); u0.y = pack2(s0.z, s0.w);
    u0.z = pack2(s1.x, s1.y); u0.w = pack2(s1.z, s1.w);
    u1.x = pack2(s2.x, s2.y); u1.y = pack2(s2.z, s2.w);
    u1.z = pack2(s3.x, s3.y); u1.w = pack2(s3.z, s3.w);
    A4[0][u0i] = u0; A4[0][u1i] = u1;
  }
  __syncthreads();

  for (int c = 0; c < 8; ++c) {
    const int cur = c & 1;
    float4 s0, s1, s2, s3;
    if (c < 7) {  // issue next chunk's global loads before the MFMA cluster
      const int o = (c + 1) * 64;
      s0 = src4[o]; s1 = src4[o + 1]; s2 = src4[o + 2]; s3 = src4[o + 3];
    }
    // compute chunk c
    const unsigned short* bp0 = Bp0 + c * 256;
    const unsigned short* bp1 = Bp1 + c * 256;
    #pragma unroll
    for (int kk = 0; kk < 8; ++kk) {
      bf16x8 a  = *reinterpret_cast<const bf16x8*>(&A4[cur][arow + ((kk * 4 + kg) ^ aswz)]);
      bf16x8 b0 = *reinterpret_cast<const bf16x8*>(bp0 + kk * 32);
      bf16x8 b1 = *reinterpret_cast<const bf16x8*>(bp1 + kk * 32);
      acc0 = __builtin_amdgcn_mfma_f32_16x16x32_bf16(a, b0, acc0, 0, 0, 0);
      acc1 = __builtin_amdgcn_mfma_f32_16x16x32_bf16(a, b1, acc1, 0, 0, 0);
    }
    if (c < 7) {
      uint4 u0, u1;
      u0.x = pack2(s0.x, s0.y); u0.y = pack2(s0.z, s0.w);
      u0.z = pack2(s1.x, s1.y); u0.w = pack2(s1.z, s1.w);
      u1.x = pack2(s2.x, s2.y); u1.y = pack2(s2.z, s2.w);
      u1.z = pack2(s3.x, s3.y); u1.w = pack2(s3.z, s3.w);
      A4[cur ^ 1][u0i] = u0; A4[cur ^ 1][u1i] = u1;
    }
    __syncthreads();
  }

  // ---- epilogue: acc -> hp, then LN + GELU
  #pragma unroll
  for (int q = 0; q < 4; ++q) {
    hp[kg * 4 + q][ch0 + bl]      = acc0[q];
    hp[kg * 4 + q][ch0 + 16 + bl] = acc1[q];
  }
  __syncthreads();

  const int row = t >> 4;
  const int c0  = t & 15;
  float v[8], g8[8], bt8[8];
  float s = 0.f, sq = 0.f;
  #pragma unroll
  for (int e = 0; e < 8; ++e) {
    const int ch = c0 + e * 16;
    v[e]  = hp[row][ch];
    g8[e] = gamma[ch];
    bt8[e] = beta[ch];
    s += v[e]; sq += v[e] * v[e];
  }
  #pragma unroll
  for (int off = 8; off; off >>= 1) { s += __shfl_xor(s, off); sq += __shfl_xor(sq, off); }
  const float mu  = s  * (1.f / 128.f);
  const float var = sq * (1.f / 128.f) - mu * mu;
  const float inv = rsqrtf(var + EPS_);
  float* orow = out0 + ((size_t)(b * N_ + i0 + row)) * OUTF_;
  #pragma unroll
  for (int e = 0; e < 8; ++e) {
    float y = (v[e] - mu) * inv * g8[e] + bt8[e];
    y *= OUT_SCALE_;
    orow[c0 + e * 16] = 0.5f * y * (1.f + erff(y * 0.70710678118654752f));
  }
}

extern "C" void kernel_launch(void* const* d_in, const int* in_sizes, int n_in,
                              void* d_out, int out_size, void* d_ws, size_t ws_size,
                              hipStream_t stream) {
  (void)in_sizes; (void)n_in; (void)out_size; (void)ws_size;
  const float* h        = (const float*)d_in[0];
  const int*   adj      = (const int*)d_in[1];
  const float* W        = (const float*)d_in[2];
  const float* alp      = (const float*)d_in[3];
  const float* arp      = (const float*)d_in[4];
  const float* aln      = (const float*)d_in[5];
  const float* arn      = (const float*)d_in[6];
  const float* rel_emb  = (const float*)d_in[7];
  const float* a_rel_p  = (const float*)d_in[8];
  const float* a_rel_n  = (const float*)d_in[9];
  const float* ll1      = (const float*)d_in[10];
  const float* lr1      = (const float*)d_in[11];
  const float* ll2      = (const float*)d_in[12];
  const float* lr2      = (const float*)d_in[13];
  const float* gamma    = (const float*)d_in[14];
  const float* beta     = (const float*)d_in[15];

  float* out0 = (float*)d_out;                          // gelu(h'): B*N*OUTF
  float* out1 = out0 + (size_t)B_ * N_ * OUTF_;         // attention: B*N*N

  float* ws    = (float*)d_ws;
  float* scal  = ws;                    // 16 floats
  float* lposv = ws + 16;               // B*N
  float* rposv = lposv + B_ * N_;
  float* lnegv = rposv + B_ * N_;
  float* rnegv = lnegv + B_ * N_;
  float* Wh    = rnegv + B_ * N_;       // B*N*OUTF fp32
  unsigned short* WhvT = (unsigned short*)(Wh + (size_t)B_ * N_ * OUTF_);  // [B][OUTF][N] bf16

  scalars_kernel<<<1, 64, 0, stream>>>(rel_emb, a_rel_p, a_rel_n, ll1, lr1, ll2, lr2, scal);
  wh_kernel<<<(B_ * N_) / 16, 256, 0, stream>>>(h, W, Wh, WhvT);
  dots_kernel<<<(B_ * N_) / 4, 256, 0, stream>>>(Wh, alp, arp, aln, arn, lposv, rposv, lnegv, rnegv);
  attn_rows_kernel<<<(B_ * N_) / 4, 256, 0, stream>>>(adj, lposv, rposv, lnegv, rnegv, scal, out1);
  pv_mfma_kernel<<<B_ * (N_ / 16), 256, 0, stream>>>(out1, WhvT, gamma, beta, out0);
}

// Round 4
// 100.227 us; speedup vs baseline: 2.8616x; 1.2821x over previous
//
#include <hip/hip_runtime.h>
#include <math.h>

typedef short bf16x8 __attribute__((ext_vector_type(8)));
typedef float f32x4  __attribute__((ext_vector_type(4)));

constexpr int   B_    = 4;
constexpr int   N_    = 2048;
constexpr int   INF_  = 256;
constexpr int   OUTF_ = 128;
constexpr float LAMBDA_INIT_ = 0.35550906759096926f;
constexpr float OUT_SCALE_   = 0.64449093240903074f;   // 1 - LAMBDA_INIT
constexpr float EPS_         = 1e-5f;
constexpr float LOG2E_       = 1.44269504088896340736f;

__device__ inline unsigned short f2bf(float x) {
  unsigned u = __float_as_uint(x);
  u += 0x7fffu + ((u >> 16) & 1u);          // round-to-nearest-even
  return (unsigned short)(u >> 16);
}
__device__ inline unsigned pack2(float a, float b) {
  return (unsigned)f2bf(a) | ((unsigned)f2bf(b) << 16);
}

// ---------------- Kernel A: tiny scalars (rel scores + lambda), pre-scaled by log2e ----------------
__global__ void scalars_kernel(const float* __restrict__ rel_emb,
                               const float* __restrict__ a_rel_pos,
                               const float* __restrict__ a_rel_neg,
                               const float* __restrict__ ll1, const float* __restrict__ lr1,
                               const float* __restrict__ ll2, const float* __restrict__ lr2,
                               float* __restrict__ scal) {
  int lane = threadIdx.x;  // 64 threads, 1 wave
  float p1 = ll1[lane] * lr1[lane];
  float p2 = ll2[lane] * lr2[lane];
  #pragma unroll
  for (int off = 32; off; off >>= 1) { p1 += __shfl_xor(p1, off); p2 += __shfl_xor(p2, off); }
  if (lane == 0) scal[12] = expf(p1) - expf(p2) + LAMBDA_INIT_;   // lam: NOT scaled
  if (lane < 6) {
    float sp = 0.f, sn = 0.f;
    for (int k = 0; k < 10; ++k) {
      float rv = rel_emb[lane * 10 + k];
      sp += rv * a_rel_pos[k];
      sn += rv * a_rel_neg[k];
    }
    scal[lane]     = sp * LOG2E_;
    scal[6 + lane] = sn * LOG2E_;
  }
}

// ---------------- Kernel B: Wh = h @ W (fp32) + transposed bf16 copy ----------------
__global__ __launch_bounds__(256) void wh_kernel(const float* __restrict__ h,
                                                 const float* __restrict__ W,
                                                 float* __restrict__ Wh,
                                                 unsigned short* __restrict__ WhvT) {
  __shared__ __align__(16) float hT[INF_][20];
  const int t = threadIdx.x;
  const size_t row0 = (size_t)blockIdx.x * 16;
  #pragma unroll
  for (int i = 0; i < 16; ++i) hT[t][i] = h[(row0 + i) * INF_ + t];
  __syncthreads();
  const int c  = t & 127;
  const int rg = t >> 7;
  float acc[8] = {0.f, 0.f, 0.f, 0.f, 0.f, 0.f, 0.f, 0.f};
  #pragma unroll 4
  for (int k = 0; k < INF_; ++k) {
    float wv = W[k * OUTF_ + c];
    const float4* hp = reinterpret_cast<const float4*>(&hT[k][rg * 8]);
    float4 h0 = hp[0], h1 = hp[1];
    acc[0] += h0.x * wv; acc[1] += h0.y * wv; acc[2] += h0.z * wv; acc[3] += h0.w * wv;
    acc[4] += h1.x * wv; acc[5] += h1.y * wv; acc[6] += h1.z * wv; acc[7] += h1.w * wv;
  }
  #pragma unroll
  for (int r = 0; r < 8; ++r) Wh[(row0 + rg * 8 + r) * OUTF_ + c] = acc[r];
  uint4 pk;
  pk.x = pack2(acc[0], acc[1]); pk.y = pack2(acc[2], acc[3]);
  pk.z = pack2(acc[4], acc[5]); pk.w = pack2(acc[6], acc[7]);
  const int b  = (int)(row0 >> 11);
  const int n0 = (int)(row0 & 2047) + rg * 8;
  *reinterpret_cast<uint4*>(WhvT + ((size_t)b * OUTF_ + c) * N_ + n0) = pk;
}

// ---------------- Kernel C: per-node dot scores, pre-scaled by log2e ----------------
__global__ __launch_bounds__(256) void dots_kernel(const float* __restrict__ Wh,
                                                   const float* __restrict__ alp, const float* __restrict__ arp,
                                                   const float* __restrict__ aln, const float* __restrict__ arn,
                                                   float* __restrict__ lposv, float* __restrict__ rposv,
                                                   float* __restrict__ lnegv, float* __restrict__ rnegv) {
  const int t = threadIdx.x;
  const int wid = t >> 6, lane = t & 63;
  const int node = blockIdx.x * 4 + wid;
  float wp = Wh[(size_t)node * OUTF_ + lane];
  float wn = Wh[(size_t)node * OUTF_ + 64 + lane];
  float s0 = wp * alp[lane], s1 = wp * arp[lane];
  float s2 = wn * aln[lane], s3 = wn * arn[lane];
  #pragma unroll
  for (int off = 32; off; off >>= 1) {
    s0 += __shfl_xor(s0, off); s1 += __shfl_xor(s1, off);
    s2 += __shfl_xor(s2, off); s3 += __shfl_xor(s3, off);
  }
  if (lane == 0) {
    lposv[node] = s0 * LOG2E_; rposv[node] = s1 * LOG2E_;
    lnegv[node] = s2 * LOG2E_; rnegv[node] = s3 * LOG2E_;
  }
}

// ---------------- Kernel D: fused attention + PV(MFMA) + LN + GELU ----------------
// 512 blocks x 512 threads (8 waves). Block: 16 rows. Phase 1: softmax (2 rows/wave),
// write fp32 attention to out1 + bf16 swizzled A-tile to LDS (64KB). Phase 2: MFMA
// 16x128 over K=2048, B = WhvT direct from global. Epilogue: LN + GELU.
__global__ __launch_bounds__(512) void fused_kernel(
    const int* __restrict__ adj,
    const float* __restrict__ lposv, const float* __restrict__ rposv,
    const float* __restrict__ lnegv, const float* __restrict__ rnegv,
    const float* __restrict__ scal, const unsigned short* __restrict__ WhvT,
    const float* __restrict__ gamma, const float* __restrict__ beta,
    float* __restrict__ out0, float* __restrict__ out1) {
  __shared__ __align__(16) unsigned char ldsraw[65536];
  uint4* A4 = reinterpret_cast<uint4*>(ldsraw);                   // [16 rows][256 units]
  float (*hp)[132] = reinterpret_cast<float (*)[132]>(ldsraw);    // epilogue overlay

  const int t = threadIdx.x;
  const int lane = t & 63;
  const int w = t >> 6;
  const int b  = blockIdx.x >> 7;
  const int i0 = (blockIdx.x & 127) * 16;

  const float lam = scal[12];
  // bpermute LUT: lane a (1..5) holds rel score; lane 0 = -1e30 (mask -> exp = 0)
  float srcP = -1.0e30f, srcN = -1.0e30f;
  if (lane >= 1 && lane <= 5) { srcP = scal[lane]; srcN = scal[6 + lane]; }
  const int iSrcP = __float_as_int(srcP);
  const int iSrcN = __float_as_int(srcN);

  // ---------------- phase 1: two rows per wave ----------------
  #pragma unroll
  for (int rr = 0; rr < 2; ++rr) {
    const int r = w * 2 + rr;
    const int flat = b * N_ + i0 + r;
    const float lP = lposv[flat];
    const float lN = lnegv[flat];
    const int*   adjRow = adj + (size_t)flat * N_;
    const float* rpB = rposv + b * N_;
    const float* rnB = rnegv + b * N_;

    float pP[32], pN[32];
    float sP = 0.f, sN = 0.f;
    #pragma unroll
    for (int c = 0; c < 4; ++c) {
      const int j0 = c * 512 + lane * 8;
      int4   a0  = *reinterpret_cast<const int4*>(adjRow + j0);
      int4   a1  = *reinterpret_cast<const int4*>(adjRow + j0 + 4);
      float4 rp0 = *reinterpret_cast<const float4*>(rpB + j0);
      float4 rp1 = *reinterpret_cast<const float4*>(rpB + j0 + 4);
      float4 rn0 = *reinterpret_cast<const float4*>(rnB + j0);
      float4 rn1 = *reinterpret_cast<const float4*>(rnB + j0 + 4);
      int   av[8] = {a0.x, a0.y, a0.z, a0.w, a1.x, a1.y, a1.z, a1.w};
      float rp[8] = {rp0.x, rp0.y, rp0.z, rp0.w, rp1.x, rp1.y, rp1.z, rp1.w};
      float rn[8] = {rn0.x, rn0.y, rn0.z, rn0.w, rn1.x, rn1.y, rn1.z, rn1.w};
      #pragma unroll
      for (int q = 0; q < 8; ++q) {
        float rsp = __int_as_float(__builtin_amdgcn_ds_bpermute(av[q] << 2, iSrcP));
        float rsn = __int_as_float(__builtin_amdgcn_ds_bpermute(av[q] << 2, iSrcN));
        float e = lP + rp[q] + rsp;
        e = fmaxf(e, 0.2f * e);                 // leaky-relu (scale>0 commutes)
        float p = __builtin_amdgcn_exp2f(e);    // logits pre-scaled by log2e
        pP[c * 8 + q] = p; sP += p;
        float en = lN + rn[q] + rsn;
        en = fmaxf(en, 0.2f * en);
        float pn = __builtin_amdgcn_exp2f(en);
        pN[c * 8 + q] = pn; sN += pn;
      }
    }
    #pragma unroll
    for (int off = 32; off; off >>= 1) { sP += __shfl_xor(sP, off); sN += __shfl_xor(sN, off); }
    const float s1 = 1.f / sP;
    const float s2 = -lam / sN;
    float* o1 = out1 + (size_t)flat * N_;
    const int swz = r & 7;
    #pragma unroll
    for (int c = 0; c < 4; ++c) {
      float a8[8];
      #pragma unroll
      for (int q = 0; q < 8; ++q) a8[q] = pP[c * 8 + q] * s1 + pN[c * 8 + q] * s2;
      const int j0 = c * 512 + lane * 8;
      *reinterpret_cast<float4*>(o1 + j0)     = make_float4(a8[0], a8[1], a8[2], a8[3]);
      *reinterpret_cast<float4*>(o1 + j0 + 4) = make_float4(a8[4], a8[5], a8[6], a8[7]);
      uint4 u;
      u.x = pack2(a8[0], a8[1]); u.y = pack2(a8[2], a8[3]);
      u.z = pack2(a8[4], a8[5]); u.w = pack2(a8[6], a8[7]);
      A4[r * 256 + ((c * 64 + lane) ^ swz)] = u;
    }
  }
  __syncthreads();

  // ---------------- phase 2: MFMA 16 rows x 128 ch, K = 2048 ----------------
  const int bl = lane & 15;    // A-row / B-col
  const int kg = lane >> 4;    // k-group
  const int ch = w * 16 + bl;
  const unsigned short* Bp = WhvT + ((size_t)b * OUTF_ + ch) * N_ + kg * 8;
  const int aswz = bl & 7;
  f32x4 acc = {0.f, 0.f, 0.f, 0.f};
  #pragma unroll 8
  for (int c2 = 0; c2 < 64; ++c2) {
    bf16x8 a  = *reinterpret_cast<const bf16x8*>(&A4[bl * 256 + ((c2 * 4 + kg) ^ aswz)]);
    bf16x8 bf = *reinterpret_cast<const bf16x8*>(Bp + c2 * 32);
    acc = __builtin_amdgcn_mfma_f32_16x16x32_bf16(a, bf, acc, 0, 0, 0);
  }
  __syncthreads();   // A-tile dead; reuse as hp
  #pragma unroll
  for (int q = 0; q < 4; ++q) hp[kg * 4 + q][ch] = acc[q];
  __syncthreads();

  // ---------------- epilogue: LN + GELU ----------------
  const int row = t >> 5;
  const int c0  = t & 31;
  float v[4], s = 0.f, sq = 0.f;
  #pragma unroll
  for (int e = 0; e < 4; ++e) {
    v[e] = hp[row][c0 + e * 32];
    s += v[e]; sq += v[e] * v[e];
  }
  #pragma unroll
  for (int off = 16; off; off >>= 1) { s += __shfl_xor(s, off); sq += __shfl_xor(sq, off); }
  const float mu  = s  * (1.f / 128.f);
  const float var = sq * (1.f / 128.f) - mu * mu;
  const float inv = rsqrtf(var + EPS_);
  float* orow = out0 + ((size_t)(b * N_ + i0 + row)) * OUTF_;
  #pragma unroll
  for (int e = 0; e < 4; ++e) {
    const int chh = c0 + e * 32;
    float y = (v[e] - mu) * inv * gamma[chh] + beta[chh];
    y *= OUT_SCALE_;
    orow[chh] = 0.5f * y * (1.f + erff(y * 0.70710678118654752f));
  }
}

extern "C" void kernel_launch(void* const* d_in, const int* in_sizes, int n_in,
                              void* d_out, int out_size, void* d_ws, size_t ws_size,
                              hipStream_t stream) {
  (void)in_sizes; (void)n_in; (void)out_size; (void)ws_size;
  const float* h        = (const float*)d_in[0];
  const int*   adj      = (const int*)d_in[1];
  const float* W        = (const float*)d_in[2];
  const float* alp      = (const float*)d_in[3];
  const float* arp      = (const float*)d_in[4];
  const float* aln      = (const float*)d_in[5];
  const float* arn      = (const float*)d_in[6];
  const float* rel_emb  = (const float*)d_in[7];
  const float* a_rel_p  = (const float*)d_in[8];
  const float* a_rel_n  = (const float*)d_in[9];
  const float* ll1      = (const float*)d_in[10];
  const float* lr1      = (const float*)d_in[11];
  const float* ll2      = (const float*)d_in[12];
  const float* lr2      = (const float*)d_in[13];
  const float* gamma    = (const float*)d_in[14];
  const float* beta     = (const float*)d_in[15];

  float* out0 = (float*)d_out;                          // gelu(h'): B*N*OUTF
  float* out1 = out0 + (size_t)B_ * N_ * OUTF_;         // attention: B*N*N

  float* ws    = (float*)d_ws;
  float* scal  = ws;                    // 16 floats
  float* lposv = ws + 16;               // B*N
  float* rposv = lposv + B_ * N_;
  float* lnegv = rposv + B_ * N_;
  float* rnegv = lnegv + B_ * N_;
  float* Wh    = rnegv + B_ * N_;       // B*N*OUTF fp32
  unsigned short* WhvT = (unsigned short*)(Wh + (size_t)B_ * N_ * OUTF_);  // [B][OUTF][N] bf16

  scalars_kernel<<<1, 64, 0, stream>>>(rel_emb, a_rel_p, a_rel_n, ll1, lr1, ll2, lr2, scal);
  wh_kernel<<<(B_ * N_) / 16, 256, 0, stream>>>(h, W, Wh, WhvT);
  dots_kernel<<<(B_ * N_) / 4, 256, 0, stream>>>(Wh, alp, arp, aln, arn, lposv, rposv, lnegv, rnegv);
  fused_kernel<<<B_ * (N_ / 16), 512, 0, stream>>>(adj, lposv, rposv, lnegv, rnegv,
                                                   scal, WhvT, gamma, beta, out0, out1);
}

// Round 8
// 97.671 us; speedup vs baseline: 2.9365x; 1.0262x over previous
//
#include <hip/hip_runtime.h>
#include <math.h>

typedef short bf16x8 __attribute__((ext_vector_type(8)));
typedef float f32x4  __attribute__((ext_vector_type(4)));

constexpr int   B_    = 4;
constexpr int   N_    = 2048;
constexpr int   INF_  = 256;
constexpr int   OUTF_ = 128;
constexpr float LAMBDA_INIT_ = 0.35550906759096926f;
constexpr float OUT_SCALE_   = 0.64449093240903074f;   // 1 - LAMBDA_INIT
constexpr float EPS_         = 1e-5f;
constexpr float LOG2E_       = 1.44269504088896340736f;

__device__ inline unsigned short f2bf(float x) {
  unsigned u = __float_as_uint(x);
  u += 0x7fffu + ((u >> 16) & 1u);          // round-to-nearest-even
  return (unsigned short)(u >> 16);
}
__device__ inline unsigned pack2(float a, float b) {
  return (unsigned)f2bf(a) | ((unsigned)f2bf(b) << 16);
}

// ---------------- Kernel A: tiny scalars (rel scores + lambda), log2e-scaled ----------------
__global__ void scalars_kernel(const float* __restrict__ rel_emb,
                               const float* __restrict__ a_rel_pos,
                               const float* __restrict__ a_rel_neg,
                               const float* __restrict__ ll1, const float* __restrict__ lr1,
                               const float* __restrict__ ll2, const float* __restrict__ lr2,
                               float* __restrict__ scal) {
  int lane = threadIdx.x;  // 64 threads, 1 wave
  float p1 = ll1[lane] * lr1[lane];
  float p2 = ll2[lane] * lr2[lane];
  #pragma unroll
  for (int off = 32; off; off >>= 1) { p1 += __shfl_xor(p1, off); p2 += __shfl_xor(p2, off); }
  if (lane == 0) scal[12] = expf(p1) - expf(p2) + LAMBDA_INIT_;   // lam: NOT scaled
  if (lane < 6) {
    float sp = 0.f, sn = 0.f;
    for (int k = 0; k < 10; ++k) {
      float rv = rel_emb[lane * 10 + k];
      sp += rv * a_rel_pos[k];
      sn += rv * a_rel_neg[k];
    }
    scal[lane]     = sp * LOG2E_;
    scal[6 + lane] = sn * LOG2E_;
  }
}

// ---------------- Kernel B: Wh = h @ W (fp32) + transposed bf16 copy ----------------
__global__ __launch_bounds__(256) void wh_kernel(const float* __restrict__ h,
                                                 const float* __restrict__ W,
                                                 float* __restrict__ Wh,
                                                 unsigned short* __restrict__ WhvT) {
  __shared__ __align__(16) float hT[INF_][20];
  const int t = threadIdx.x;
  const size_t row0 = (size_t)blockIdx.x * 16;
  #pragma unroll
  for (int i = 0; i < 16; ++i) hT[t][i] = h[(row0 + i) * INF_ + t];
  __syncthreads();
  const int c  = t & 127;
  const int rg = t >> 7;
  float acc[8] = {0.f, 0.f, 0.f, 0.f, 0.f, 0.f, 0.f, 0.f};
  #pragma unroll 4
  for (int k = 0; k < INF_; ++k) {
    float wv = W[k * OUTF_ + c];
    const float4* hp = reinterpret_cast<const float4*>(&hT[k][rg * 8]);
    float4 h0 = hp[0], h1 = hp[1];
    acc[0] += h0.x * wv; acc[1] += h0.y * wv; acc[2] += h0.z * wv; acc[3] += h0.w * wv;
    acc[4] += h1.x * wv; acc[5] += h1.y * wv; acc[6] += h1.z * wv; acc[7] += h1.w * wv;
  }
  #pragma unroll
  for (int r = 0; r < 8; ++r) Wh[(row0 + rg * 8 + r) * OUTF_ + c] = acc[r];
  uint4 pk;
  pk.x = pack2(acc[0], acc[1]); pk.y = pack2(acc[2], acc[3]);
  pk.z = pack2(acc[4], acc[5]); pk.w = pack2(acc[6], acc[7]);
  const int b  = (int)(row0 >> 11);
  const int n0 = (int)(row0 & 2047) + rg * 8;
  *reinterpret_cast<uint4*>(WhvT + ((size_t)b * OUTF_ + c) * N_ + n0) = pk;
}

// ---------------- Kernel C: per-node dot scores, pre-scaled by log2e ----------------
__global__ __launch_bounds__(256) void dots_kernel(const float* __restrict__ Wh,
                                                   const float* __restrict__ alp, const float* __restrict__ arp,
                                                   const float* __restrict__ aln, const float* __restrict__ arn,
                                                   float* __restrict__ lposv, float* __restrict__ rposv,
                                                   float* __restrict__ lnegv, float* __restrict__ rnegv) {
  const int t = threadIdx.x;
  const int wid = t >> 6, lane = t & 63;
  const int node = blockIdx.x * 4 + wid;
  float wp = Wh[(size_t)node * OUTF_ + lane];
  float wn = Wh[(size_t)node * OUTF_ + 64 + lane];
  float s0 = wp * alp[lane], s1 = wp * arp[lane];
  float s2 = wn * aln[lane], s3 = wn * arn[lane];
  #pragma unroll
  for (int off = 32; off; off >>= 1) {
    s0 += __shfl_xor(s0, off); s1 += __shfl_xor(s1, off);
    s2 += __shfl_xor(s2, off); s3 += __shfl_xor(s3, off);
  }
  if (lane == 0) {
    lposv[node] = s0 * LOG2E_; rposv[node] = s1 * LOG2E_;
    lnegv[node] = s2 * LOG2E_; rnegv[node] = s3 * LOG2E_;
  }
}

// ---------------- Kernel D1: attention rows, high-occupancy (8 j's/thread) ----------------
// 8192 blocks x 256 threads = one row per block; thread t covers j = t*8..t*8+7.
// Numerics identical to r4's passing phase 1 (fp32, no-max exp2, fp32 normalize).
// Also emits bf16-packed attention panel (same pack2 values r3's pv staged).
__global__ __launch_bounds__(256) void attn_v3(
    const int* __restrict__ adj,
    const float* __restrict__ lposv, const float* __restrict__ rposv,
    const float* __restrict__ lnegv, const float* __restrict__ rnegv,
    const float* __restrict__ scal, float* __restrict__ out1,
    unsigned short* __restrict__ abf, int writeAbf) {
  __shared__ float sums[8];   // [P:0..3 | N:4..7] per wave
  const int t = threadIdx.x;
  const int lane = t & 63;
  const int wv = t >> 6;
  const int flat = blockIdx.x;        // b*N + i
  const int b = flat >> 11;

  const float lam = scal[12];
  float srcP = -1.0e30f, srcN = -1.0e30f;
  if (lane >= 1 && lane <= 5) { srcP = scal[lane]; srcN = scal[6 + lane]; }
  const int iSrcP = __float_as_int(srcP);
  const int iSrcN = __float_as_int(srcN);

  const float lP = lposv[flat];
  const float lN = lnegv[flat];
  const int j0 = t * 8;
  const int4*   a4  = reinterpret_cast<const int4*>(adj + (size_t)flat * N_ + j0);
  const float4* rp4 = reinterpret_cast<const float4*>(rposv + b * N_ + j0);
  const float4* rn4 = reinterpret_cast<const float4*>(rnegv + b * N_ + j0);
  int4   av0 = a4[0],  av1 = a4[1];
  float4 rp0 = rp4[0], rp1 = rp4[1];
  float4 rn0 = rn4[0], rn1 = rn4[1];
  int   av[8] = {av0.x, av0.y, av0.z, av0.w, av1.x, av1.y, av1.z, av1.w};
  float rp[8] = {rp0.x, rp0.y, rp0.z, rp0.w, rp1.x, rp1.y, rp1.z, rp1.w};
  float rn[8] = {rn0.x, rn0.y, rn0.z, rn0.w, rn1.x, rn1.y, rn1.z, rn1.w};

  float p[8], n[8];
  float sPa = 0.f, sPb = 0.f, sNa = 0.f, sNb = 0.f;
  #pragma unroll
  for (int q = 0; q < 8; ++q) {
    float rsp = __int_as_float(__builtin_amdgcn_ds_bpermute(av[q] << 2, iSrcP));
    float rsn = __int_as_float(__builtin_amdgcn_ds_bpermute(av[q] << 2, iSrcN));
    float e  = lP + rp[q] + rsp;
    float en = lN + rn[q] + rsn;
    e  = fmaxf(e, 0.2f * e);                 // leaky (pos scale commutes with log2e)
    en = fmaxf(en, 0.2f * en);
    p[q] = __builtin_amdgcn_exp2f(e);
    n[q] = __builtin_amdgcn_exp2f(en);
    if (q & 1) { sPb += p[q]; sNb += n[q]; } else { sPa += p[q]; sNa += n[q]; }
  }
  float sP = sPa + sPb, sN = sNa + sNb;
  #pragma unroll
  for (int off = 32; off; off >>= 1) { sP += __shfl_xor(sP, off); sN += __shfl_xor(sN, off); }
  if (lane == 0) { sums[wv] = sP; sums[4 + wv] = sN; }
  __syncthreads();
  const float sPT = (sums[0] + sums[1]) + (sums[2] + sums[3]);
  const float sNT = (sums[4] + sums[5]) + (sums[6] + sums[7]);
  const float s1 = 1.f / sPT;
  const float s2 = -lam / sNT;

  float a[8];
  #pragma unroll
  for (int q = 0; q < 8; ++q) a[q] = p[q] * s1 + n[q] * s2;
  float* o1 = out1 + (size_t)flat * N_ + j0;
  *reinterpret_cast<float4*>(o1)     = make_float4(a[0], a[1], a[2], a[3]);
  *reinterpret_cast<float4*>(o1 + 4) = make_float4(a[4], a[5], a[6], a[7]);
  if (writeAbf) {
    uint4 u;
    u.x = pack2(a[0], a[1]); u.y = pack2(a[2], a[3]);
    u.z = pack2(a[4], a[5]); u.w = pack2(a[6], a[7]);
    *reinterpret_cast<uint4*>(abf + (size_t)flat * N_ + j0) = u;
  }
}

// ---------------- Kernel D2: PV via MFMA (r3-verbatim structure) + LN + GELU ----------------
// 512 blocks x 256 threads (4 waves). Block: 16 rows x 128 ch, K = 2048 in 8 chunks of 256.
// A staged into XOR-swizzled LDS from either the bf16 panel (fast) or fp32 out1 (fallback).
__global__ __launch_bounds__(256) void pv_v4(
    const float* __restrict__ attn, const unsigned short* __restrict__ abf, int useAbf,
    const unsigned short* __restrict__ WhvT,
    const float* __restrict__ gamma, const float* __restrict__ beta,
    float* __restrict__ out0) {
  __shared__ __align__(16) uint4 A4[2][16 * 32];   // [buf][row*32 + unit(16B)], 16KB
  __shared__ __align__(16) float hp[16][132];
  const int t = threadIdx.x;
  const int lane = t & 63;
  const int w = t >> 6;
  const int bi = blockIdx.x;
  const int b  = bi >> 7;
  const int i0 = (bi & 127) * 16;

  // ---- staging coords: thread covers row sr, 16 values starting at col sj*16
  const int sr = t >> 4;
  const int sj = t & 15;
  const float4* src4 = reinterpret_cast<const float4*>(
      attn + ((size_t)(b * N_ + i0 + sr)) * N_ + sj * 16);
  const uint4* srcU = reinterpret_cast<const uint4*>(
      abf + ((size_t)(b * N_ + i0 + sr)) * N_) + sj * 2;
  const int swz = sr & 7;
  const int u0i = sr * 32 + ((sj * 2)     ^ swz);
  const int u1i = sr * 32 + ((sj * 2 + 1) ^ swz);

  // ---- compute coords (r3 verbatim)
  const int ch0 = w * 32;
  const int bl  = lane & 15;   // A row / B ch within tile
  const int kg  = lane >> 4;   // k-group
  const unsigned short* Bp0 = WhvT + ((size_t)b * OUTF_ + ch0 + bl) * N_ + kg * 8;
  const unsigned short* Bp1 = Bp0 + (size_t)16 * N_;
  f32x4 acc0 = {0.f, 0.f, 0.f, 0.f};
  f32x4 acc1 = {0.f, 0.f, 0.f, 0.f};
  const int arow = bl * 32;
  const int aswz = bl & 7;

  // stage chunk 0
  if (useAbf) {
    A4[0][u0i] = srcU[0]; A4[0][u1i] = srcU[1];
  } else {
    float4 s0 = src4[0], s1 = src4[1], s2 = src4[2], s3 = src4[3];
    uint4 u0, u1;
    u0.x = pack2(s0.x, s0.y); u0.y = pack2(s0.z, s0.w);
    u0.z = pack2(s1.x, s1.y); u0.w = pack2(s1.z, s1.w);
    u1.x = pack2(s2.x, s2.y); u1.y = pack2(s2.z, s2.w);
    u1.z = pack2(s3.x, s3.y); u1.w = pack2(s3.z, s3.w);
    A4[0][u0i] = u0; A4[0][u1i] = u1;
  }
  __syncthreads();

  for (int c = 0; c < 8; ++c) {
    const int cur = c & 1;
    float4 s0, s1, s2, s3;
    uint4 t0, t1;
    if (c < 7) {  // issue next chunk's global loads before the MFMA cluster
      if (useAbf) {
        t0 = srcU[(c + 1) * 32]; t1 = srcU[(c + 1) * 32 + 1];
      } else {
        const int o = (c + 1) * 64;
        s0 = src4[o]; s1 = src4[o + 1]; s2 = src4[o + 2]; s3 = src4[o + 3];
      }
    }
    // compute chunk c (r3 verbatim)
    const unsigned short* bp0 = Bp0 + c * 256;
    const unsigned short* bp1 = Bp1 + c * 256;
    #pragma unroll
    for (int kk = 0; kk < 8; ++kk) {
      bf16x8 a  = *reinterpret_cast<const bf16x8*>(&A4[cur][arow + ((kk * 4 + kg) ^ aswz)]);
      bf16x8 b0 = *reinterpret_cast<const bf16x8*>(bp0 + kk * 32);
      bf16x8 b1 = *reinterpret_cast<const bf16x8*>(bp1 + kk * 32);
      acc0 = __builtin_amdgcn_mfma_f32_16x16x32_bf16(a, b0, acc0, 0, 0, 0);
      acc1 = __builtin_amdgcn_mfma_f32_16x16x32_bf16(a, b1, acc1, 0, 0, 0);
    }
    if (c < 7) {
      if (useAbf) {
        A4[cur ^ 1][u0i] = t0; A4[cur ^ 1][u1i] = t1;
      } else {
        uint4 u0, u1;
        u0.x = pack2(s0.x, s0.y); u0.y = pack2(s0.z, s0.w);
        u0.z = pack2(s1.x, s1.y); u0.w = pack2(s1.z, s1.w);
        u1.x = pack2(s2.x, s2.y); u1.y = pack2(s2.z, s2.w);
        u1.z = pack2(s3.x, s3.y); u1.w = pack2(s3.z, s3.w);
        A4[cur ^ 1][u0i] = u0; A4[cur ^ 1][u1i] = u1;
      }
    }
    __syncthreads();
  }

  // ---- epilogue: acc -> hp, then LN + GELU (r3 verbatim)
  #pragma unroll
  for (int q = 0; q < 4; ++q) {
    hp[kg * 4 + q][ch0 + bl]      = acc0[q];
    hp[kg * 4 + q][ch0 + 16 + bl] = acc1[q];
  }
  __syncthreads();

  const int row = t >> 4;
  const int c0  = t & 15;
  float v[8], g8[8], bt8[8];
  float s = 0.f, sq = 0.f;
  #pragma unroll
  for (int e = 0; e < 8; ++e) {
    const int ch = c0 + e * 16;
    v[e]  = hp[row][ch];
    g8[e] = gamma[ch];
    bt8[e] = beta[ch];
    s += v[e]; sq += v[e] * v[e];
  }
  #pragma unroll
  for (int off = 8; off; off >>= 1) { s += __shfl_xor(s, off); sq += __shfl_xor(sq, off); }
  const float mu  = s  * (1.f / 128.f);
  const float var = sq * (1.f / 128.f) - mu * mu;
  const float inv = rsqrtf(var + EPS_);
  float* orow = out0 + ((size_t)(b * N_ + i0 + row)) * OUTF_;
  #pragma unroll
  for (int e = 0; e < 8; ++e) {
    float y = (v[e] - mu) * inv * g8[e] + bt8[e];
    y *= OUT_SCALE_;
    orow[c0 + e * 16] = 0.5f * y * (1.f + erff(y * 0.70710678118654752f));
  }
}

extern "C" void kernel_launch(void* const* d_in, const int* in_sizes, int n_in,
                              void* d_out, int out_size, void* d_ws, size_t ws_size,
                              hipStream_t stream) {
  (void)in_sizes; (void)n_in; (void)out_size;
  const float* h        = (const float*)d_in[0];
  const int*   adj      = (const int*)d_in[1];
  const float* W        = (const float*)d_in[2];
  const float* alp      = (const float*)d_in[3];
  const float* arp      = (const float*)d_in[4];
  const float* aln      = (const float*)d_in[5];
  const float* arn      = (const float*)d_in[6];
  const float* rel_emb  = (const float*)d_in[7];
  const float* a_rel_p  = (const float*)d_in[8];
  const float* a_rel_n  = (const float*)d_in[9];
  const float* ll1      = (const float*)d_in[10];
  const float* lr1      = (const float*)d_in[11];
  const float* ll2      = (const float*)d_in[12];
  const float* lr2      = (const float*)d_in[13];
  const float* gamma    = (const float*)d_in[14];
  const float* beta     = (const float*)d_in[15];

  float* out0 = (float*)d_out;                          // gelu(h'): B*N*OUTF
  float* out1 = out0 + (size_t)B_ * N_ * OUTF_;         // attention: B*N*N

  float* ws    = (float*)d_ws;
  float* scal  = ws;                    // 32 floats
  float* lposv = ws + 32;               // B*N
  float* rposv = lposv + B_ * N_;
  float* lnegv = rposv + B_ * N_;
  float* rnegv = lnegv + B_ * N_;
  float* Wh    = rnegv + B_ * N_;       // B*N*OUTF fp32
  unsigned short* WhvT = (unsigned short*)(Wh + (size_t)B_ * N_ * OUTF_);  // [B][OUTF][N] bf16
  unsigned short* Abf  = WhvT + (size_t)B_ * N_ * OUTF_;                   // [B*N][N] bf16

  // ws budget gate for the bf16 attention panel
  const size_t need = (size_t)(32 + 4 * B_ * N_ + B_ * N_ * OUTF_) * 4
                    + (size_t)B_ * N_ * OUTF_ * 2
                    + (size_t)B_ * N_ * N_ * 2;
  const int useAbf = (ws_size >= need) ? 1 : 0;

  scalars_kernel<<<1, 64, 0, stream>>>(rel_emb, a_rel_p, a_rel_n, ll1, lr1, ll2, lr2, scal);
  wh_kernel<<<(B_ * N_) / 16, 256, 0, stream>>>(h, W, Wh, WhvT);
  dots_kernel<<<(B_ * N_) / 4, 256, 0, stream>>>(Wh, alp, arp, aln, arn, lposv, rposv, lnegv, rnegv);
  attn_v3<<<B_ * N_, 256, 0, stream>>>(adj, lposv, rposv, lnegv, rnegv, scal, out1, Abf, useAbf);
  pv_v4<<<B_ * (N_ / 16), 256, 0, stream>>>(out1, Abf, useAbf, WhvT, gamma, beta, out0);
}

// Round 10
// 97.181 us; speedup vs baseline: 2.9513x; 1.0050x over previous
//
#include <hip/hip_runtime.h>
#include <math.h>

typedef short bf16x8 __attribute__((ext_vector_type(8)));
typedef float f32x4  __attribute__((ext_vector_type(4)));

constexpr int   B_    = 4;
constexpr int   N_    = 2048;
constexpr int   INF_  = 256;
constexpr int   OUTF_ = 128;
constexpr float LAMBDA_INIT_ = 0.35550906759096926f;
constexpr float OUT_SCALE_   = 0.64449093240903074f;   // 1 - LAMBDA_INIT
constexpr float EPS_         = 1e-5f;
constexpr float LOG2E_       = 1.44269504088896340736f;

__device__ inline unsigned short f2bf(float x) {
  unsigned u = __float_as_uint(x);
  u += 0x7fffu + ((u >> 16) & 1u);          // round-to-nearest-even
  return (unsigned short)(u >> 16);
}
__device__ inline unsigned pack2(float a, float b) {
  return (unsigned)f2bf(a) | ((unsigned)f2bf(b) << 16);
}

// ---------------- Kernel A: tiny scalars (rel scores + lambda), log2e-scaled ----------------
__global__ void scalars_kernel(const float* __restrict__ rel_emb,
                               const float* __restrict__ a_rel_pos,
                               const float* __restrict__ a_rel_neg,
                               const float* __restrict__ ll1, const float* __restrict__ lr1,
                               const float* __restrict__ ll2, const float* __restrict__ lr2,
                               float* __restrict__ scal) {
  int lane = threadIdx.x;  // 64 threads, 1 wave
  float p1 = ll1[lane] * lr1[lane];
  float p2 = ll2[lane] * lr2[lane];
  #pragma unroll
  for (int off = 32; off; off >>= 1) { p1 += __shfl_xor(p1, off); p2 += __shfl_xor(p2, off); }
  if (lane == 0) scal[12] = expf(p1) - expf(p2) + LAMBDA_INIT_;   // lam: NOT scaled
  if (lane < 6) {
    float sp = 0.f, sn = 0.f;
    for (int k = 0; k < 10; ++k) {
      float rv = rel_emb[lane * 10 + k];
      sp += rv * a_rel_pos[k];
      sn += rv * a_rel_neg[k];
    }
    scal[lane]     = sp * LOG2E_;
    scal[6 + lane] = sn * LOG2E_;
  }
}

// ---------------- Kernel B: Wh = h @ W (fp32) + transposed bf16 copy ----------------
__global__ __launch_bounds__(256) void wh_kernel(const float* __restrict__ h,
                                                 const float* __restrict__ W,
                                                 float* __restrict__ Wh,
                                                 unsigned short* __restrict__ WhvT) {
  __shared__ __align__(16) float hT[INF_][20];
  const int t = threadIdx.x;
  const size_t row0 = (size_t)blockIdx.x * 16;
  #pragma unroll
  for (int i = 0; i < 16; ++i) hT[t][i] = h[(row0 + i) * INF_ + t];
  __syncthreads();
  const int c  = t & 127;
  const int rg = t >> 7;
  float acc[8] = {0.f, 0.f, 0.f, 0.f, 0.f, 0.f, 0.f, 0.f};
  #pragma unroll 4
  for (int k = 0; k < INF_; ++k) {
    float wv = W[k * OUTF_ + c];
    const float4* hp = reinterpret_cast<const float4*>(&hT[k][rg * 8]);
    float4 h0 = hp[0], h1 = hp[1];
    acc[0] += h0.x * wv; acc[1] += h0.y * wv; acc[2] += h0.z * wv; acc[3] += h0.w * wv;
    acc[4] += h1.x * wv; acc[5] += h1.y * wv; acc[6] += h1.z * wv; acc[7] += h1.w * wv;
  }
  #pragma unroll
  for (int r = 0; r < 8; ++r) Wh[(row0 + rg * 8 + r) * OUTF_ + c] = acc[r];
  uint4 pk;
  pk.x = pack2(acc[0], acc[1]); pk.y = pack2(acc[2], acc[3]);
  pk.z = pack2(acc[4], acc[5]); pk.w = pack2(acc[6], acc[7]);
  const int b  = (int)(row0 >> 11);
  const int n0 = (int)(row0 & 2047) + rg * 8;
  *reinterpret_cast<uint4*>(WhvT + ((size_t)b * OUTF_ + c) * N_ + n0) = pk;
}

// ---------------- Kernel C: per-node dot scores, pre-scaled by log2e ----------------
__global__ __launch_bounds__(256) void dots_kernel(const float* __restrict__ Wh,
                                                   const float* __restrict__ alp, const float* __restrict__ arp,
                                                   const float* __restrict__ aln, const float* __restrict__ arn,
                                                   float* __restrict__ lposv, float* __restrict__ rposv,
                                                   float* __restrict__ lnegv, float* __restrict__ rnegv) {
  const int t = threadIdx.x;
  const int wid = t >> 6, lane = t & 63;
  const int node = blockIdx.x * 4 + wid;
  float wp = Wh[(size_t)node * OUTF_ + lane];
  float wn = Wh[(size_t)node * OUTF_ + 64 + lane];
  float s0 = wp * alp[lane], s1 = wp * arp[lane];
  float s2 = wn * aln[lane], s3 = wn * arn[lane];
  #pragma unroll
  for (int off = 32; off; off >>= 1) {
    s0 += __shfl_xor(s0, off); s1 += __shfl_xor(s1, off);
    s2 += __shfl_xor(s2, off); s3 += __shfl_xor(s3, off);
  }
  if (lane == 0) {
    lposv[node] = s0 * LOG2E_; rposv[node] = s1 * LOG2E_;
    lnegv[node] = s2 * LOG2E_; rnegv[node] = s3 * LOG2E_;
  }
}

// ---------------- Kernel D1: attention rows, 4 j's/thread (short chains, high occupancy) ----------------
// 8192 blocks x 512 threads = one row per block; thread t covers j = t*4..t*4+3.
// Numerics identical to r8's passing attn_v3 (fp32, no-max exp2, fp32 normalize).
__global__ __launch_bounds__(512) void attn_v3b(
    const int* __restrict__ adj,
    const float* __restrict__ lposv, const float* __restrict__ rposv,
    const float* __restrict__ lnegv, const float* __restrict__ rnegv,
    const float* __restrict__ scal, float* __restrict__ out1,
    unsigned short* __restrict__ abf, int writeAbf) {
  __shared__ float sums[16];   // [P:0..7 | N:8..15] per wave
  const int t = threadIdx.x;
  const int lane = t & 63;
  const int wv = t >> 6;
  const int flat = blockIdx.x;        // b*N + i
  const int b = flat >> 11;

  const float lam = scal[12];
  float srcP = -1.0e30f, srcN = -1.0e30f;
  if (lane >= 1 && lane <= 5) { srcP = scal[lane]; srcN = scal[6 + lane]; }
  const int iSrcP = __float_as_int(srcP);
  const int iSrcN = __float_as_int(srcN);

  const float lP = lposv[flat];
  const float lN = lnegv[flat];
  const int j0 = t * 4;
  int4   av4 = *reinterpret_cast<const int4*>(adj + (size_t)flat * N_ + j0);
  float4 rp4 = *reinterpret_cast<const float4*>(rposv + b * N_ + j0);
  float4 rn4 = *reinterpret_cast<const float4*>(rnegv + b * N_ + j0);
  int   av[4] = {av4.x, av4.y, av4.z, av4.w};
  float rp[4] = {rp4.x, rp4.y, rp4.z, rp4.w};
  float rn[4] = {rn4.x, rn4.y, rn4.z, rn4.w};

  float p[4], n[4];
  #pragma unroll
  for (int q = 0; q < 4; ++q) {
    float rsp = __int_as_float(__builtin_amdgcn_ds_bpermute(av[q] << 2, iSrcP));
    float rsn = __int_as_float(__builtin_amdgcn_ds_bpermute(av[q] << 2, iSrcN));
    float e  = lP + rp[q] + rsp;
    float en = lN + rn[q] + rsn;
    e  = fmaxf(e, 0.2f * e);                 // leaky (pos scale commutes with log2e)
    en = fmaxf(en, 0.2f * en);
    p[q] = __builtin_amdgcn_exp2f(e);
    n[q] = __builtin_amdgcn_exp2f(en);
  }
  float sP = (p[0] + p[1]) + (p[2] + p[3]);
  float sN = (n[0] + n[1]) + (n[2] + n[3]);
  #pragma unroll
  for (int off = 32; off; off >>= 1) { sP += __shfl_xor(sP, off); sN += __shfl_xor(sN, off); }
  if (lane == 0) { sums[wv] = sP; sums[8 + wv] = sN; }
  __syncthreads();
  const float sPT = ((sums[0] + sums[1]) + (sums[2] + sums[3])) +
                    ((sums[4] + sums[5]) + (sums[6] + sums[7]));
  const float sNT = ((sums[8] + sums[9]) + (sums[10] + sums[11])) +
                    ((sums[12] + sums[13]) + (sums[14] + sums[15]));
  const float s1 = 1.f / sPT;
  const float s2 = -lam / sNT;

  float a[4];
  #pragma unroll
  for (int q = 0; q < 4; ++q) a[q] = p[q] * s1 + n[q] * s2;
  float* o1 = out1 + (size_t)flat * N_ + j0;
  *reinterpret_cast<float4*>(o1) = make_float4(a[0], a[1], a[2], a[3]);
  if (writeAbf) {
    uint2 u;
    u.x = pack2(a[0], a[1]); u.y = pack2(a[2], a[3]);
    *reinterpret_cast<uint2*>(abf + (size_t)flat * N_ + j0) = u;
  }
}

// ---------------- Kernel D2: PV via MFMA, 8 waves (one 16-ch tile each, 2 acc chains) ----------------
// 512 blocks x 512 threads. Block: 16 rows x 128 ch, K = 2048 in 8 chunks of 256.
// A staged into XOR-swizzled LDS (1 uint4/thread) from bf16 panel (or fp32 fallback).
// FIX vs r9: chunk stride is 32 uint4 (not 16) / 64 float4 (not 32) — one chunk = 256 bf16.
__global__ __launch_bounds__(512) void pv_v5(
    const float* __restrict__ attn, const unsigned short* __restrict__ abf, int useAbf,
    const unsigned short* __restrict__ WhvT,
    const float* __restrict__ gamma, const float* __restrict__ beta,
    float* __restrict__ out0) {
  __shared__ __align__(16) uint4 A4[2][16 * 32];   // [buf][row*32 + unit(16B)], 16KB
  __shared__ __align__(16) float hp[16][132];
  const int t = threadIdx.x;
  const int lane = t & 63;
  const int w = t >> 6;
  const int bi = blockIdx.x;
  const int b  = bi >> 7;
  const int i0 = (bi & 127) * 16;

  // ---- staging coords: thread covers row sr, one 16B unit sj (8 bf16 = 8 k's)
  const int sr = t >> 5;
  const int sj = t & 31;
  const float4* src4 = reinterpret_cast<const float4*>(
      attn + ((size_t)(b * N_ + i0 + sr)) * N_ + sj * 8);
  const uint4* srcU = reinterpret_cast<const uint4*>(
      abf + ((size_t)(b * N_ + i0 + sr)) * N_) + sj;
  const int swz = sr & 7;
  const int ui = sr * 32 + (sj ^ swz);

  // ---- compute coords: wave w owns ch tile [w*16, w*16+16)
  const int bl  = lane & 15;   // A row / B ch within tile
  const int kg  = lane >> 4;   // k-group
  const int ch  = w * 16 + bl;
  const unsigned short* Bp = WhvT + ((size_t)b * OUTF_ + ch) * N_ + kg * 8;
  f32x4 acc0 = {0.f, 0.f, 0.f, 0.f};   // even chunks
  f32x4 acc1 = {0.f, 0.f, 0.f, 0.f};   // odd chunks
  const int arow = bl * 32;
  const int aswz = bl & 7;

  // stage chunk 0
  if (useAbf) {
    A4[0][ui] = srcU[0];
  } else {
    float4 s0 = src4[0], s1 = src4[1];
    uint4 u;
    u.x = pack2(s0.x, s0.y); u.y = pack2(s0.z, s0.w);
    u.z = pack2(s1.x, s1.y); u.w = pack2(s1.z, s1.w);
    A4[0][ui] = u;
  }
  __syncthreads();

  for (int c = 0; c < 8; ++c) {
    const int cur = c & 1;
    float4 s0, s1;
    uint4 t0;
    if (c < 7) {  // issue next chunk's global loads before the MFMA cluster
      if (useAbf) {
        t0 = srcU[(c + 1) * 32];             // 32 uint4 per 256-k chunk
      } else {
        const int o = (c + 1) * 64;          // 64 float4 per 256-k chunk
        s0 = src4[o]; s1 = src4[o + 1];
      }
    }
    // compute chunk c
    const unsigned short* bp = Bp + c * 256;
    #pragma unroll
    for (int kk = 0; kk < 8; ++kk) {
      bf16x8 a  = *reinterpret_cast<const bf16x8*>(&A4[cur][arow + ((kk * 4 + kg) ^ aswz)]);
      bf16x8 bv = *reinterpret_cast<const bf16x8*>(bp + kk * 32);
      if (cur == 0) acc0 = __builtin_amdgcn_mfma_f32_16x16x32_bf16(a, bv, acc0, 0, 0, 0);
      else          acc1 = __builtin_amdgcn_mfma_f32_16x16x32_bf16(a, bv, acc1, 0, 0, 0);
    }
    if (c < 7) {
      if (useAbf) {
        A4[cur ^ 1][ui] = t0;
      } else {
        uint4 u;
        u.x = pack2(s0.x, s0.y); u.y = pack2(s0.z, s0.w);
        u.z = pack2(s1.x, s1.y); u.w = pack2(s1.z, s1.w);
        A4[cur ^ 1][ui] = u;
      }
    }
    __syncthreads();
  }

  // ---- epilogue: acc -> hp, then LN + GELU (r4's 512-thread epilogue, verbatim)
  #pragma unroll
  for (int q = 0; q < 4; ++q) hp[kg * 4 + q][ch] = acc0[q] + acc1[q];
  __syncthreads();

  const int row = t >> 5;
  const int c0  = t & 31;
  float v[4], s = 0.f, sq = 0.f;
  #pragma unroll
  for (int e = 0; e < 4; ++e) {
    v[e] = hp[row][c0 + e * 32];
    s += v[e]; sq += v[e] * v[e];
  }
  #pragma unroll
  for (int off = 16; off; off >>= 1) { s += __shfl_xor(s, off); sq += __shfl_xor(sq, off); }
  const float mu  = s  * (1.f / 128.f);
  const float var = sq * (1.f / 128.f) - mu * mu;
  const float inv = rsqrtf(var + EPS_);
  float* orow = out0 + ((size_t)(b * N_ + i0 + row)) * OUTF_;
  #pragma unroll
  for (int e = 0; e < 4; ++e) {
    const int chh = c0 + e * 32;
    float y = (v[e] - mu) * inv * gamma[chh] + beta[chh];
    y *= OUT_SCALE_;
    orow[chh] = 0.5f * y * (1.f + erff(y * 0.70710678118654752f));
  }
}

extern "C" void kernel_launch(void* const* d_in, const int* in_sizes, int n_in,
                              void* d_out, int out_size, void* d_ws, size_t ws_size,
                              hipStream_t stream) {
  (void)in_sizes; (void)n_in; (void)out_size;
  const float* h        = (const float*)d_in[0];
  const int*   adj      = (const int*)d_in[1];
  const float* W        = (const float*)d_in[2];
  const float* alp      = (const float*)d_in[3];
  const float* arp      = (const float*)d_in[4];
  const float* aln      = (const float*)d_in[5];
  const float* arn      = (const float*)d_in[6];
  const float* rel_emb  = (const float*)d_in[7];
  const float* a_rel_p  = (const float*)d_in[8];
  const float* a_rel_n  = (const float*)d_in[9];
  const float* ll1      = (const float*)d_in[10];
  const float* lr1      = (const float*)d_in[11];
  const float* ll2      = (const float*)d_in[12];
  const float* lr2      = (const float*)d_in[13];
  const float* gamma    = (const float*)d_in[14];
  const float* beta     = (const float*)d_in[15];

  float* out0 = (float*)d_out;                          // gelu(h'): B*N*OUTF
  float* out1 = out0 + (size_t)B_ * N_ * OUTF_;         // attention: B*N*N

  float* ws    = (float*)d_ws;
  float* scal  = ws;                    // 32 floats
  float* lposv = ws + 32;               // B*N
  float* rposv = lposv + B_ * N_;
  float* lnegv = rposv + B_ * N_;
  float* rnegv = lnegv + B_ * N_;
  float* Wh    = rnegv + B_ * N_;       // B*N*OUTF fp32
  unsigned short* WhvT = (unsigned short*)(Wh + (size_t)B_ * N_ * OUTF_);  // [B][OUTF][N] bf16
  unsigned short* Abf  = WhvT + (size_t)B_ * N_ * OUTF_;                   // [B*N][N] bf16

  // ws budget gate for the bf16 attention panel
  const size_t need = (size_t)(32 + 4 * B_ * N_ + B_ * N_ * OUTF_) * 4
                    + (size_t)B_ * N_ * OUTF_ * 2
                    + (size_t)B_ * N_ * N_ * 2;
  const int useAbf = (ws_size >= need) ? 1 : 0;

  scalars_kernel<<<1, 64, 0, stream>>>(rel_emb, a_rel_p, a_rel_n, ll1, lr1, ll2, lr2, scal);
  wh_kernel<<<(B_ * N_) / 16, 256, 0, stream>>>(h, W, Wh, WhvT);
  dots_kernel<<<(B_ * N_) / 4, 256, 0, stream>>>(Wh, alp, arp, aln, arn, lposv, rposv, lnegv, rnegv);
  attn_v3b<<<B_ * N_, 512, 0, stream>>>(adj, lposv, rposv, lnegv, rnegv, scal, out1, Abf, useAbf);
  pv_v5<<<B_ * (N_ / 16), 512, 0, stream>>>(out1, Abf, useAbf, WhvT, gamma, beta, out0);
}